// Round 1
// baseline (105.979 us; speedup 1.0000x reference)
//
#include <hip/hip_runtime.h>
#include <math.h>

// NonLinearReadoutBlock: per row n (N=100000):
//   x_s = x[n, :128]; x_v = x[n, 128:512] viewed (128,3) [c fastest]
//   h_s = x_s @ W1_s * inv1 + b1_s                  (32)
//   h_v[o][c] = sum_i x_v[i][c] * W1_v[i][o] * inv1 (16x3)
//   s = silu(h_s[:16]); g = silu(h_s[16:])
//   out[:10] = s @ W2_s * 0.25 + b2_s
//   out[10:13] = sum_o g[o]*h_v[o][c]*W2_v[o] * 0.25
// Memory-bound: 2048 B in / 52 B out per row, ~10.5 kFLOP per row.

#define TILE 16     // rows per block-iteration (16*512 f32 = 32KB contiguous)
#define BLOCK 256   // 4 waves; 16 threads per row

__global__ __launch_bounds__(BLOCK, 2) void nlrb_kernel(
    const float* __restrict__ x,
    const float* __restrict__ W1s,   // (128,32) row-major
    const float* __restrict__ W1v,   // (128,16)
    const float* __restrict__ b1s,   // (32)
    const float* __restrict__ W2s,   // (16,10)
    const float* __restrict__ W2v,   // (16,1)
    const float* __restrict__ b2s,   // (10)
    float* __restrict__ out,         // (N,13)
    int N)
{
    // x tile, row stride 516 floats: +4 pad => rows land 4 banks apart, so the
    // 4 distinct row addresses in a wave (16-lane broadcast each) never collide.
    __shared__ float xs[TILE][516];
    // W1_s interleaved: w1p[i][j] = {W1_s[i][j], W1_s[i][j+16]} -> one b64 read
    // per (i,j); 16 lanes hit banks {2j,2j+1} = all 32 banks, broadcast x4 rows.
    __shared__ float w1p[128][16][2];
    __shared__ float w1v[128][16];   // natural; bank (16i+j)%32, conflict-free
    __shared__ float wcomb[16][13];  // [j][e]: e<10 -> W2_s[j][e], else W2_v[j]
    __shared__ float bcomb[13];      // e<10 -> b2_s[e], else 0
    __shared__ float b1l[32];
    // per-row layer-2 operands: [row][j] = {silu(h_s[j]), g*hv0, g*hv1, g*hv2}
    __shared__ float sred[TILE][17][4];  // row stride 68 words: rows spread banks

    const int tid = threadIdx.x;

    // ---- one-time weight staging ----
    for (int idx = tid; idx < 128 * 32; idx += BLOCK) {
        int i = idx >> 5, o = idx & 31;
        w1p[i][o & 15][o >> 4] = W1s[idx];
    }
    for (int idx = tid; idx < 128 * 16; idx += BLOCK)
        (&w1v[0][0])[idx] = W1v[idx];
    if (tid < 32) b1l[tid] = b1s[tid];
    if (tid < 16 * 13) {
        int jj = tid / 13, e = tid % 13;
        wcomb[jj][e] = (e < 10) ? W2s[jj * 10 + e] : W2v[jj];
    }
    if (tid < 13) bcomb[tid] = (tid < 10) ? b2s[tid] : 0.0f;
    __syncthreads();

    const int row = tid >> 4;   // 0..15  (row within tile)
    const int j   = tid & 15;   // 0..15  (hidden-unit slot)
    const float inv1 = 0.08838834764831843f;  // 1/sqrt(128)
    const int ntiles = N / TILE;              // N=100000 -> 6250, exact

    for (int tile = blockIdx.x; tile < ntiles; tile += gridDim.x) {
        // ---- stage 16 rows (contiguous 32KB) -> LDS, fully coalesced ----
        const float4* src = (const float4*)(x + (size_t)tile * (TILE * 512));
        #pragma unroll
        for (int k = 0; k < 8; ++k) {
            int f = tid + k * BLOCK;        // float4 index within tile [0,2048)
            int r = f >> 7, c4 = f & 127;   // 128 float4 per row
            *(float4*)&xs[r][c4 * 4] = src[f];
        }
        __syncthreads();

        // ---- layer 1: thread j of row-group computes h_s[j], h_s[j+16],
        //      h_v[j][0..2].  x reads broadcast across the 16-lane group. ----
        float h0 = 0.f, h1 = 0.f, a0 = 0.f, a1 = 0.f, a2 = 0.f;
        #pragma unroll 8
        for (int i0 = 0; i0 < 128; i0 += 4) {
            float4 s4  = *(const float4*)&xs[row][i0];
            float4 v4a = *(const float4*)&xs[row][128 + 3 * i0];
            float4 v4b = *(const float4*)&xs[row][128 + 3 * i0 + 4];
            float4 v4c = *(const float4*)&xs[row][128 + 3 * i0 + 8];
            float xsv[4]  = {s4.x, s4.y, s4.z, s4.w};
            float xvv[12] = {v4a.x, v4a.y, v4a.z, v4a.w,
                             v4b.x, v4b.y, v4b.z, v4b.w,
                             v4c.x, v4c.y, v4c.z, v4c.w};
            #pragma unroll
            for (int di = 0; di < 4; ++di) {
                int i = i0 + di;
                float2 w = *(const float2*)&w1p[i][j][0];
                float wv = w1v[i][j];
                h0 = fmaf(xsv[di], w.x, h0);
                h1 = fmaf(xsv[di], w.y, h1);
                a0 = fmaf(xvv[3 * di + 0], wv, a0);
                a1 = fmaf(xvv[3 * di + 1], wv, a1);
                a2 = fmaf(xvv[3 * di + 2], wv, a2);
            }
        }
        h0 = fmaf(h0, inv1, b1l[j]);
        h1 = fmaf(h1, inv1, b1l[j + 16]);
        a0 *= inv1; a1 *= inv1; a2 *= inv1;
        float s = h0 / (1.f + expf(-h0));   // silu
        float g = h1 / (1.f + expf(-h1));
        float4 o4 = make_float4(s, g * a0, g * a1, g * a2);
        *(float4*)&sred[row][j][0] = o4;
        __syncthreads();

        // ---- layer 2: 208 threads, one (row, output-elem) each ----
        if (tid < TILE * 13) {
            int r = tid / 13, e = tid % 13;
            int slot = (e < 10) ? 0 : (e - 9);   // 0 = scalars, 1..3 = gated xyz
            float sum = 0.f;
            #pragma unroll
            for (int jj = 0; jj < 16; ++jj)
                sum = fmaf(sred[r][jj][slot], wcomb[jj][e], sum);
            out[(size_t)(tile * TILE + r) * 13 + e] = fmaf(sum, 0.25f, bcomb[e]);
        }
        __syncthreads();  // sred/xs reuse protected by next iteration's barriers:
                          // this barrier keeps compute(sred write, t+1) after
                          // out-phase(sred read, t) ordering via stage+B1.
    }
}

extern "C" void kernel_launch(void* const* d_in, const int* in_sizes, int n_in,
                              void* d_out, int out_size, void* d_ws, size_t ws_size,
                              hipStream_t stream) {
    const float* x   = (const float*)d_in[0];
    const float* W1s = (const float*)d_in[1];
    const float* W1v = (const float*)d_in[2];
    const float* b1s = (const float*)d_in[3];
    const float* W2s = (const float*)d_in[4];
    const float* W2v = (const float*)d_in[5];
    const float* b2s = (const float*)d_in[6];
    float* outp = (float*)d_out;
    const int N = in_sizes[0] / 512;   // 100000
    nlrb_kernel<<<dim3(512), dim3(BLOCK), 0, stream>>>(
        x, W1s, W1v, b1s, W2s, W2v, b2s, outp, N);
}